// Round 4
// baseline (302.936 us; speedup 1.0000x reference)
//
#include <hip/hip_runtime.h>
#include <hip/hip_bf16.h>

typedef __bf16 bf16_t;
typedef __attribute__((ext_vector_type(8))) __bf16 bf16x8;
typedef __attribute__((ext_vector_type(4))) __bf16 bf16x4;
typedef __attribute__((ext_vector_type(4))) float floatx4;

#define NB 8192   // rows of x (B)
#define NC 8192   // rows of y (C)
#define ND 256    // feature dim D
#define BM 128
#define BN 128
#define BK 64     // 4 K-iters
#define LOG2E 1.44269504088896340736f

typedef __attribute__((address_space(3))) void lds_void_t;
typedef __attribute__((address_space(1))) void gl_void_t;

// ---------------------------------------------------------------------------
// prep: fp32 -> bf16 copies of x and y, plus SCALED row squared-norms:
//   x2s[r] = gamma * log2(e) * ||x_r||^2   (same for y2s)
// One wave per row (256 floats = 64 lanes x float4).
// ---------------------------------------------------------------------------
__global__ __launch_bounds__(256) void prep_kernel(
    const float* __restrict__ x, const float* __restrict__ y,
    const float* __restrict__ gamma_p,
    bf16_t* __restrict__ xb, bf16_t* __restrict__ yb,
    float* __restrict__ x2s, float* __restrict__ y2s)
{
    int t    = threadIdx.x;
    int wave = t >> 6;
    int lane = t & 63;
    int row  = blockIdx.x * 4 + wave;   // 0..16383 (x rows then y rows)

    const float* src;
    bf16_t* dst;
    float* nrm;
    int r;
    if (row < NB) { src = x; dst = xb; nrm = x2s; r = row; }
    else          { src = y; dst = yb; nrm = y2s; r = row - NB; }

    float4 v = ((const float4*)(src + (size_t)r * ND))[lane];
    float ss = v.x * v.x + v.y * v.y + v.z * v.z + v.w * v.w;

    bf16x4 o;
    o.x = (__bf16)v.x; o.y = (__bf16)v.y; o.z = (__bf16)v.z; o.w = (__bf16)v.w;
    ((bf16x4*)(dst + (size_t)r * ND))[lane] = o;

    #pragma unroll
    for (int off = 32; off >= 1; off >>= 1)
        ss += __shfl_xor(ss, off, 64);
    if (lane == 0) nrm[r] = ss * (LOG2E * gamma_p[0]);
}

// ---------------------------------------------------------------------------
// RBF GEMM: out[b,c] = 2^( min( A2*dot(x_b,y_c) - (x2s[b]+y2s[c]), 0 ) ).
// 128x128 tile, BK=64, 256 threads (4 waves 2x2), wave = 64x64 subtile.
// Round-2/3 changes (store/L2-path focus):
//  * 2D XCD swizzle: each XCD owns a 32x16-tile region -> working set
//    2MB(x)+1MB(y) = 3MB < 4MB per-XCD L2 (vs 8MB round-robin thrash).
//  * Epilogue: per-wave LDS transpose (row stride 272B: <=2-way banks on
//    both the 4B writes and b128 reads) -> floatx4 NON-TEMPORAL stores.
//    256B contiguous per quarter-wave, 4x fewer store instrs, nt keeps the
//    256MB output stream from evicting the L2-resident xb/yb panels.
// ---------------------------------------------------------------------------
__global__ __launch_bounds__(256, 3) void rbf_gemm_kernel(
    const bf16_t* __restrict__ xb, const bf16_t* __restrict__ yb,
    const float* __restrict__ x2s, const float* __restrict__ y2s,
    const float* __restrict__ gamma_p, float* __restrict__ out)
{
    __shared__ bf16_t lA[BM * BK];                  // 16 KB swizzled 128x64
    __shared__ bf16_t lB[BN * BK];                  // 16 KB
    __shared__ __align__(16) float eT[4][16 * 68];  // 17 KB: per-wave 16x64 (+4 pad)

    const int t    = threadIdx.x;
    const int lane = t & 63;
    const int wave = t >> 6;
    const int wm   = wave >> 1;
    const int wn   = wave & 1;
    const int quad = lane >> 4;
    const int l15  = lane & 15;

    // --- XCD-aware 2D tile swizzle (dispatch order: blockIdx.x fastest) ---
    // n%8 = XCD; XCDs arranged 4x2 over the 64x64 tile grid; each XCD walks
    // a 32(M) x 16(N) tile region x-fastest.
    const unsigned n   = blockIdx.y * 64u + blockIdx.x;
    const unsigned xcd = n & 7u;
    const unsigned s   = n >> 3;            // 0..511 within XCD
    const unsigned tbm = (xcd & 1u) * 32u + (s & 31u);   // M-tile 0..63
    const unsigned tbn = (xcd >> 1) * 16u + (s >> 5);    // N-tile 0..63

    const int bm = (int)tbm * BM;           // x-row base
    const int bn = (int)tbn * BN;           // y-row (output col) base

    const float A2 = 2.0f * LOG2E * gamma_p[0];

    floatx4 acc[4][4];
    #pragma unroll
    for (int i = 0; i < 4; ++i)
        #pragma unroll
        for (int j = 0; j < 4; ++j)
            acc[i][j] = (floatx4){0.f, 0.f, 0.f, 0.f};

    // Staging: 16 KB tile = 1024 x 16B chunks; thread t, call c owns chunk
    // li = c*256+t -> row = li>>3, k-byte = (li&7)*16, source col XOR-swizzled
    // (linear LDS dest + pre-swizzled global source, rule #21).
    const char* gA = (const char*)xb + (size_t)bm * (ND * 2);
    const char* gB = (const char*)yb + (size_t)bn * (ND * 2);

    for (int kt = 0; kt < ND / BK; ++kt) {          // 4 iterations
        __syncthreads();
        #pragma unroll
        for (int c = 0; c < 4; ++c) {
            const int li  = c * 256 + t;
            const int row = li >> 3;
            const int kb  = (li & 7) * 16;
            const int kbs = kb ^ ((row & 7) << 4);
            const size_t goff = (size_t)row * (ND * 2) + kt * (BK * 2) + kbs;
            __builtin_amdgcn_global_load_lds(
                (gl_void_t*)(gA + goff),
                (lds_void_t*)((char*)lA + (size_t)li * 16), 16, 0, 0);
            __builtin_amdgcn_global_load_lds(
                (gl_void_t*)(gB + goff),
                (lds_void_t*)((char*)lB + (size_t)li * 16), 16, 0, 0);
        }
        __syncthreads();

        #pragma unroll
        for (int kk = 0; kk < 2; ++kk) {
            bf16x8 af[4], bfr[4];
            const int swz = ((l15 & 7) << 4);
            const int off = (kk * 64 + quad * 16) ^ swz;
            #pragma unroll
            for (int i = 0; i < 4; ++i) {
                const int ar = wm * 64 + i * 16 + l15;
                af[i]  = *(const bf16x8*)((const char*)lA + ar * (BK * 2) + off);
                const int br = wn * 64 + i * 16 + l15;
                bfr[i] = *(const bf16x8*)((const char*)lB + br * (BK * 2) + off);
            }
            #pragma unroll
            for (int i = 0; i < 4; ++i)
                #pragma unroll
                for (int j = 0; j < 4; ++j)
                    acc[i][j] = __builtin_amdgcn_mfma_f32_16x16x32_bf16(
                        af[i], bfr[j], acc[i][j], 0, 0, 0);
        }
    }

    // --- Epilogue: compute -> per-wave LDS transpose -> floatx4 nt stores ---
    // C/D layout: col = lane&15, row = quad*4 + reg [m89/m91].
    float* ep = &eT[wave][0];
    const int rr = lane >> 4;               // row sub-index for readback

    #pragma unroll
    for (int i = 0; i < 4; ++i) {
        const int grow0 = bm + wm * 64 + i * 16 + quad * 4;
        float xn[4];
        #pragma unroll
        for (int r = 0; r < 4; ++r) xn[r] = x2s[grow0 + r];

        // ensure previous slice's b128 reads retired before overwrite
        asm volatile("s_waitcnt lgkmcnt(0)" ::: "memory");

        #pragma unroll
        for (int j = 0; j < 4; ++j) {
            const int gcol = bn + wn * 64 + j * 16 + l15;
            const float yn = y2s[gcol];
            #pragma unroll
            for (int r = 0; r < 4; ++r) {
                float t2 = fmaf(A2, acc[i][j][r], -(xn[r] + yn));
                t2 = fminf(t2, 0.0f);
                // write transposed slice: row = quad*4+r (stride 68 dwords),
                // col = j*16+l15.  Banks: 2-way max (68 mod 32 = 4 rotation).
                ep[(quad * 4 + r) * 68 + j * 16 + l15] = exp2f(t2);
            }
        }
        // same-wave RAW through LDS: wait for writes before readback
        asm volatile("s_waitcnt lgkmcnt(0)" ::: "memory");

        const int growb = bm + wm * 64 + i * 16;
        float* orow_base = out + (size_t)growb * NC + bn + wn * 64 + l15 * 4;
        #pragma unroll
        for (int q = 0; q < 4; ++q) {
            const int row = q * 4 + rr;     // 0..15
            floatx4 v4 = *(const floatx4*)&ep[row * 68 + l15 * 4];
            __builtin_nontemporal_store(v4,
                (floatx4*)(orow_base + (size_t)row * NC));
        }
    }
}

extern "C" void kernel_launch(void* const* d_in, const int* in_sizes, int n_in,
                              void* d_out, int out_size, void* d_ws, size_t ws_size,
                              hipStream_t stream) {
    const float* x = (const float*)d_in[0];
    const float* y = (const float*)d_in[1];
    const float* gamma = (const float*)d_in[2];
    float* out = (float*)d_out;

    // Workspace layout: xb (4 MB) | yb (4 MB) | x2s (32 KB) | y2s (32 KB)
    bf16_t* xb = (bf16_t*)d_ws;
    bf16_t* yb = xb + (size_t)NB * ND;
    float*  x2s = (float*)(yb + (size_t)NC * ND);
    float*  y2s = x2s + NB;

    prep_kernel<<<dim3((NB + NC) / 4), dim3(256), 0, stream>>>(
        x, y, gamma, xb, yb, x2s, y2s);
    rbf_gemm_kernel<<<dim3(NB / BM, NC / BN), dim3(256), 0, stream>>>(
        xb, yb, x2s, y2s, gamma, out);
}